// Round 1
// baseline (462.783 us; speedup 1.0000x reference)
//
#include <hip/hip_runtime.h>
#include <math.h>

#define XD 48
#define YD 48
#define ZD 48
#define CD 64
#define NGT 10
#define NB 2
#define KP 128
#define MVOX (XD*YD*ZD)   // 110592
#define ANCH 12.0f
#define BLK_PER_BATCH 432 // MVOX/256

// ---------------- conv: pred[b][x][y][z][o] = conv3d(feat, W) + bias ----------------
// feat logical [b][c][x][y][z] = feat_zyx[b][c][z][y][x]  (x fastest in memory)
__global__ __launch_bounds__(512) void conv_kernel(const float* __restrict__ feat_zyx,
                                                   const float* __restrict__ Wt,
                                                   const float* __restrict__ cbias,
                                                   float* __restrict__ pred) {
  __shared__ float tile[1000]; // [dz][dy][dx] 10x10x10, dx <-> memory-x
  const int tx = threadIdx.x, ty = threadIdx.y, tz = threadIdx.z;
  const int tid = tz*64 + ty*8 + tx;
  const int bx = blockIdx.x*8, by = blockIdx.y*8;
  const int b  = blockIdx.z / 6;
  const int bz = (blockIdx.z % 6)*8;

  float acc[7];
  #pragma unroll
  for (int o = 0; o < 7; ++o) acc[o] = cbias[o];

  const float* fb = feat_zyx + (size_t)b * CD * MVOX;
  for (int c = 0; c < CD; ++c) {
    const float* fc = fb + (size_t)c * MVOX;
    for (int i = tid; i < 1000; i += 512) {
      int dz = i / 100, dy = (i / 10) % 10, dx = i % 10;
      int gx = bx + dx - 1, gy = by + dy - 1, gz = bz + dz - 1;
      float v = 0.f;
      if (gx >= 0 && gx < XD && gy >= 0 && gy < YD && gz >= 0 && gz < ZD)
        v = fc[gz*(YD*XD) + gy*XD + gx];
      tile[i] = v;
    }
    __syncthreads();
    const float* Wc = Wt + c*27;
    #pragma unroll
    for (int kd = 0; kd < 3; ++kd)     // kd <-> x
      #pragma unroll
      for (int kh = 0; kh < 3; ++kh)   // kh <-> y
        #pragma unroll
        for (int kw = 0; kw < 3; ++kw) { // kw <-> z
          float v = tile[(tz+kw)*100 + (ty+kh)*10 + (tx+kd)];
          int ki = kd*9 + kh*3 + kw;
          #pragma unroll
          for (int o = 0; o < 7; ++o)
            acc[o] = fmaf(v, Wc[o*(CD*27) + ki], acc[o]);
        }
    __syncthreads();
  }
  const int gx = bx+tx, gy = by+ty, gz = bz+tz;
  size_t base = ((size_t)b*MVOX + gx*(YD*ZD) + gy*ZD + gz) * 7;
  #pragma unroll
  for (int o = 0; o < 7; ++o) pred[base + o] = acc[o];
}

// ---------------- loss: masks + bce + smoothL1 partials, pred_obj ----------------
__global__ __launch_bounds__(256) void loss_kernel(const float* __restrict__ pred,
                                                   const float* __restrict__ lrt,
                                                   const float* __restrict__ scores,
                                                   float* __restrict__ pobj,
                                                   float* __restrict__ partials) {
  const int blk = blockIdx.x;
  const int b = blk / BLK_PER_BATCH;
  const int v = (blk % BLK_PER_BATCH) * 256 + threadIdx.x;
  const int x = v / (YD*ZD), y = (v / ZD) % YD, z = v % ZD;
  const float* p = pred + ((size_t)b*MVOX + v) * 7;
  float pv[7];
  #pragma unroll
  for (int k = 0; k < 7; ++k) pv[k] = p[k];
  const float l = pv[0];
  pobj[(size_t)b*MVOX + v] = 1.f / (1.f + expf(-l));

  const float fx = (float)x, fy = (float)y, fz = (float)z;
  float cum = 0.f, sneg = 0.f;
  float a[6] = {0.f,0.f,0.f,0.f,0.f,0.f};
  #pragma unroll
  for (int n = 0; n < NGT; ++n) {
    const float* g = lrt + (b*NGT + n)*19;
    float l0 = g[0], l1 = g[1], l2 = g[2];
    float t0 = g[6], t1 = g[10], t2 = g[14];
    float sc = scores[b*NGT + n];
    float d0 = t0 - fx, d1 = t1 - fy, d2 = t2 - fz;
    float od = fmaxf(fmaxf(fabsf(d0)/(l0*0.5f + 1e-5f),
                           fabsf(d1)/(l1*0.5f + 1e-5f)),
                           fabsf(d2)/(l2*0.5f + 1e-5f));
    float mp = (od < 0.5f) ? sc : 0.f;
    float mn = (od < 0.8f) ? sc : 0.f;
    float prev = (cum >= 0.5f) ? 1.f : 0.f;
    float ctb = mp * (1.f - prev);
    a[0] += ctb * (d0 / ANCH);
    a[1] += ctb * (d1 / ANCH);
    a[2] += ctb * (d2 / ANCH);
    a[3] += ctb * logf(l0 / ANCH);
    a[4] += ctb * logf(l1 / ANCH);
    a[5] += ctb * logf(l2 / ANCH);
    cum += mp; sneg += mn;
  }
  const float pos = (cum  >= 0.5f) ? 1.f : 0.f;
  const float neg = 1.f - ((sneg >= 0.5f) ? 1.f : 0.f);
  const float bce = fmaxf(l, 0.f) - l*pos + log1pf(expf(-fabsf(l)));
  float sl = 0.f;
  #pragma unroll
  for (int c = 0; c < 6; ++c) {
    float dd = pos * pv[1+c] - pos * a[c];
    float ad = fabsf(dd);
    sl += (ad < (1.f/9.f)) ? dd*dd*4.5f : (ad - (1.f/18.f));
  }

  float vals5[5] = {bce*pos, bce*neg, pos, neg, sl};
  __shared__ float red[4][5];
  const int lane = threadIdx.x & 63, wid = threadIdx.x >> 6;
  #pragma unroll
  for (int k = 0; k < 5; ++k)
    for (int off = 32; off; off >>= 1)
      vals5[k] += __shfl_down(vals5[k], off);
  if (lane == 0) {
    #pragma unroll
    for (int k = 0; k < 5; ++k) red[wid][k] = vals5[k];
  }
  __syncthreads();
  if (threadIdx.x == 0) {
    #pragma unroll
    for (int k = 0; k < 5; ++k)
      partials[blk*5 + k] = red[0][k] + red[1][k] + red[2][k] + red[3][k];
  }
}

// ---------------- finalize total_loss ----------------
__global__ __launch_bounds__(64) void finalize_kernel(const float* __restrict__ partials,
                                                      float* __restrict__ out_loss) {
  const int lane = threadIdx.x;
  double acc[7] = {0,0,0,0,0,0,0}; // bp, bn, neg, pos0, pos1, sl0, sl1
  for (int i = lane; i < 2*BLK_PER_BATCH; i += 64) {
    const float* p = partials + i*5;
    acc[0] += p[0]; acc[1] += p[1]; acc[2] += p[3];
    if (i < BLK_PER_BATCH) { acc[3] += p[2]; acc[5] += p[4]; }
    else                   { acc[4] += p[2]; acc[6] += p[4]; }
  }
  #pragma unroll
  for (int k = 0; k < 7; ++k)
    for (int off = 32; off; off >>= 1)
      acc[k] += __shfl_down(acc[k], off);
  if (lane == 0) {
    double posg = acc[3] + acc[4];
    double cls_pos = acc[0] / (posg + 1e-6);
    double cls_neg = acc[1] / (acc[2] + 1e-6);
    double loss_prob = 1.5*cls_pos + cls_neg;
    double ps0 = fmax(acc[3], 1.0), ps1 = fmax(acc[4], 1.0);
    double loss_reg = (acc[5]/ps0 + acc[6]/ps1) / (double)NB;
    out_loss[0] = (float)(loss_prob + loss_reg);
  }
}

// ---------------- top-k: 4-pass radix select on float bit keys ----------------
__global__ __launch_bounds__(1024) void topk_kernel(const float* __restrict__ pobj,
                                                    float* __restrict__ tval,
                                                    int* __restrict__ tidx) {
  const int b = blockIdx.x;
  const float* v = pobj + (size_t)b*MVOX;
  const unsigned tid = threadIdx.x;
  __shared__ unsigned hist[256];
  __shared__ unsigned sPrefix;
  __shared__ int sRemain;
  __shared__ unsigned rKey[KP];
  __shared__ int rIdx[KP];
  __shared__ int gtCount, eqCount;
  __shared__ int eqList[1024];
  __shared__ unsigned long long comp[KP];

  if (tid == 0) { sPrefix = 0; sRemain = KP; }
  __syncthreads();

  for (int p = 0; p < 4; ++p) {
    const int shift = 24 - 8*p;
    if (tid < 256) hist[tid] = 0;
    __syncthreads();
    const unsigned pref = sPrefix;
    for (int i = tid; i < MVOX; i += 1024) {
      unsigned k = __float_as_uint(v[i]);
      bool match = (p == 0) || ((k >> (shift + 8)) == pref);
      if (match) atomicAdd(&hist[(k >> shift) & 255], 1u);
    }
    __syncthreads();
    if (tid == 0) {
      int need = sRemain; unsigned cum = 0;
      for (int bin = 255; bin >= 0; --bin) {
        unsigned h = hist[bin];
        if (cum + h >= (unsigned)need) {
          sRemain = need - (int)cum;
          sPrefix = (pref << 8) | (unsigned)bin;
          break;
        }
        cum += h;
      }
    }
    __syncthreads();
  }
  const unsigned T = sPrefix;
  const int needEq = sRemain;

  if (tid == 0) { gtCount = 0; eqCount = 0; }
  __syncthreads();
  for (int i = tid; i < MVOX; i += 1024) {
    unsigned k = __float_as_uint(v[i]);
    if (k > T)      { int p2 = atomicAdd(&gtCount, 1); rKey[p2] = k; rIdx[p2] = i; }
    else if (k == T){ int p2 = atomicAdd(&eqCount, 1); if (p2 < 1024) eqList[p2] = i; }
  }
  __syncthreads();
  const int ec = min(eqCount, 1024);
  if (ec > needEq) { // need the smallest needEq tie indices: sort ascending
    if ((int)tid >= ec) eqList[tid] = 0x7FFFFFFF;
    __syncthreads();
    for (int k = 2; k <= 1024; k <<= 1)
      for (int jj = k >> 1; jj > 0; jj >>= 1) {
        int ixj = tid ^ jj;
        if (ixj > (int)tid) {
          int aa = eqList[tid], cc = eqList[ixj];
          bool up = ((tid & k) == 0);
          if ((aa > cc) == up) { eqList[tid] = cc; eqList[ixj] = aa; }
        }
        __syncthreads();
      }
  }
  if ((int)tid < needEq) { rKey[gtCount + tid] = T; rIdx[gtCount + tid] = eqList[tid]; }
  __syncthreads();
  // sort 128 by (val desc, idx asc): ascending on (~key, idx)
  if (tid < KP) comp[tid] = ((unsigned long long)(~rKey[tid]) << 32) | (unsigned)rIdx[tid];
  __syncthreads();
  for (int k = 2; k <= KP; k <<= 1)
    for (int jj = k >> 1; jj > 0; jj >>= 1) {
      if (tid < KP) {
        int ixj = tid ^ jj;
        if (ixj > (int)tid) {
          unsigned long long aa = comp[tid], cc = comp[ixj];
          bool up = ((tid & k) == 0);
          if ((aa > cc) == up) { comp[tid] = cc; comp[ixj] = aa; }
        }
      }
      __syncthreads();
    }
  if (tid < KP) {
    unsigned long long cc = comp[tid];
    tidx[b*KP + tid] = (int)(cc & 0xffffffffull);
    tval[b*KP + tid] = __uint_as_float(~(unsigned)(cc >> 32));
  }
}

// ---------------- NMS + outputs ----------------
__device__ inline float iou2(const float* A, const float* Bb) {
  float lo1 = fmaxf(A[0], Bb[0]), lo2 = fmaxf(A[1], Bb[1]);
  float hi1 = fminf(A[2], Bb[2]), hi2 = fminf(A[3], Bb[3]);
  float inter = fmaxf(hi1 - lo1, 0.f) * fmaxf(hi2 - lo2, 0.f);
  float aA = (A[2]-A[0])*(A[3]-A[1]);
  float aB = (Bb[2]-Bb[0])*(Bb[3]-Bb[1]);
  return inter / (aA + aB - inter + 1e-9f);
}

__global__ __launch_bounds__(128) void nms_kernel(const float* __restrict__ pred,
                                                  const float* __restrict__ tval,
                                                  const int* __restrict__ tidx,
                                                  const float* __restrict__ lrt,
                                                  const float* __restrict__ scores,
                                                  float* __restrict__ out_boxes,
                                                  float* __restrict__ out_scores,
                                                  float* __restrict__ out_keep,
                                                  float* __restrict__ out_ovr) {
  const int b = blockIdx.x, j = threadIdx.x;
  __shared__ float Bxy[KP][4], Bzx[KP][4];
  __shared__ unsigned long long RowXY[KP][2], RowZX[KP][2];
  __shared__ unsigned long long keepS[2];
  __shared__ unsigned char validArr[KP];
  __shared__ float Gmin[NGT][3], Gmax[NGT][3], Gvol[NGT], Gsc[NGT];

  const float val = tval[b*KP + j];
  const int idx = tidx[b*KP + j];
  const int xi = idx / (YD*ZD), yi = (idx / ZD) % YD, zi = idx % ZD;
  const float* pd = pred + ((size_t)b*MVOX + idx) * 7;
  float d0 = pd[1], d1 = pd[2], d2 = pd[3], d3 = pd[4], d4 = pd[5], d5 = pd[6];
  float cx = (float)xi + d0*ANCH, cy = (float)yi + d1*ANCH, cz = (float)zi + d2*ANCH;
  float hx = 0.5f*expf(d3)*ANCH, hy = 0.5f*expf(d4)*ANCH, hz = 0.5f*expf(d5)*ANCH;
  float bm0 = cx - hx, bm1 = cy - hy, bm2 = cz - hz;
  float bM0 = cx + hx, bM1 = cy + hy, bM2 = cz + hz;
  const bool valid = val > 0.9f;
  validArr[j] = valid ? 1 : 0;
  float vm0 = valid ? bm0 : 0.f, vm1 = valid ? bm1 : 0.f, vm2 = valid ? bm2 : 0.f;
  float vM0 = valid ? bM0 : 0.f, vM1 = valid ? bM1 : 0.f, vM2 = valid ? bM2 : 0.f;
  Bxy[j][0] = vm1; Bxy[j][1] = vm2; Bxy[j][2] = vM1; Bxy[j][3] = vM2;
  Bzx[j][0] = vm0; Bzx[j][1] = vm2; Bzx[j][2] = vM0; Bzx[j][3] = vM2;

  if (j < NGT) {
    const float* g = lrt + (b*NGT + j)*19;
    float l0 = g[0], l1 = g[1], l2 = g[2];
    float R00=g[3],R01=g[4],R02=g[5],  t0=g[6];
    float R10=g[7],R11=g[8],R12=g[9],  t1=g[10];
    float R20=g[11],R21=g[12],R22=g[13],t2=g[14];
    float mn0=1e30f,mn1=1e30f,mn2=1e30f,mx0=-1e30f,mx1=-1e30f,mx2=-1e30f;
    #pragma unroll
    for (int s = 0; s < 8; ++s) {
      float sx = (s & 4) ? 0.5f : -0.5f;
      float sy = (s & 2) ? 0.5f : -0.5f;
      float sz = (s & 1) ? 0.5f : -0.5f;
      float px = sx*l0, py = sy*l1, pz = sz*l2;
      float c0 = R00*px + R01*py + R02*pz + t0;
      float c1 = R10*px + R11*py + R12*pz + t1;
      float c2 = R20*px + R21*py + R22*pz + t2;
      mn0 = fminf(mn0, c0); mx0 = fmaxf(mx0, c0);
      mn1 = fminf(mn1, c1); mx1 = fmaxf(mx1, c1);
      mn2 = fminf(mn2, c2); mx2 = fmaxf(mx2, c2);
    }
    Gmin[j][0]=mn0; Gmin[j][1]=mn1; Gmin[j][2]=mn2;
    Gmax[j][0]=mx0; Gmax[j][1]=mx1; Gmax[j][2]=mx2;
    Gvol[j] = (mx0-mn0)*(mx1-mn1)*(mx2-mn2);
    Gsc[j] = (scores[b*NGT + j] > 0.f) ? 1.f : 0.f;
  }
  __syncthreads();

  unsigned long long rx0=0, rx1=0, rz0=0, rz1=0;
  for (int i = 0; i < KP; ++i) {
    bool bx_ = iou2(Bxy[j], Bxy[i]) > 0.2f;
    bool bz_ = iou2(Bzx[j], Bzx[i]) > 0.2f;
    if (i < 64) { if (bx_) rx0 |= 1ull << i;      if (bz_) rz0 |= 1ull << i; }
    else        { if (bx_) rx1 |= 1ull << (i-64); if (bz_) rz1 |= 1ull << (i-64); }
  }
  RowXY[j][0]=rx0; RowXY[j][1]=rx1; RowZX[j][0]=rz0; RowZX[j][1]=rz1;
  __syncthreads();

  if (j == 0) {
    unsigned long long kx0=0,kx1=0,kz0=0,kz1=0;
    for (int i = 0; i < KP; ++i) {
      unsigned long long m0, m1;
      if (i < 64) { m0 = (i==0) ? 0ull : ((1ull<<i)-1ull); m1 = 0ull; }
      else        { m0 = ~0ull; m1 = (i==64) ? 0ull : ((1ull<<(i-64))-1ull); }
      bool supx = ((RowXY[i][0] & kx0 & m0) | (RowXY[i][1] & kx1 & m1)) != 0ull;
      bool supz = ((RowZX[i][0] & kz0 & m0) | (RowZX[i][1] & kz1 & m1)) != 0ull;
      bool vv = validArr[i] != 0;
      if (vv && !supx) { if (i<64) kx0 |= 1ull<<i; else kx1 |= 1ull<<(i-64); }
      if (vv && !supz) { if (i<64) kz0 |= 1ull<<i; else kz1 |= 1ull<<(i-64); }
    }
    keepS[0] = kx0 | kz0; keepS[1] = kx1 | kz1;
  }
  __syncthreads();

  const bool keep = (j < 64) ? ((keepS[0] >> j) & 1ull) : ((keepS[1] >> (j-64)) & 1ull);
  const float kf = keep ? 1.f : 0.f;
  float* ob = out_boxes + ((size_t)b*KP + j)*6;
  ob[0] = cx*kf; ob[1] = cy*kf; ob[2] = cz*kf;
  ob[3] = (bM0-bm0)*kf; ob[4] = (bM1-bm1)*kf; ob[5] = (bM2-bm2)*kf;
  out_scores[b*KP + j] = val * kf;
  out_keep[b*KP + j] = kf;
  const float volA = (bM0-bm0)*(bM1-bm1)*(bM2-bm2);
  for (int n = 0; n < NGT; ++n) {
    float lo0 = fmaxf(bm0, Gmin[n][0]), lo1 = fmaxf(bm1, Gmin[n][1]), lo2 = fmaxf(bm2, Gmin[n][2]);
    float hi0 = fminf(bM0, Gmax[n][0]), hi1 = fminf(bM1, Gmax[n][1]), hi2 = fminf(bM2, Gmax[n][2]);
    float inter = fmaxf(hi0-lo0, 0.f)*fmaxf(hi1-lo1, 0.f)*fmaxf(hi2-lo2, 0.f);
    float iou3 = inter / (volA + Gvol[n] - inter + 1e-9f);
    out_ovr[((size_t)b*KP + j)*NGT + n] = iou3 * kf * Gsc[n];
  }
}

extern "C" void kernel_launch(void* const* d_in, const int* in_sizes, int n_in,
                              void* d_out, int out_size, void* d_ws, size_t ws_size,
                              hipStream_t stream) {
  const float* lrt    = (const float*)d_in[0];
  const float* scores = (const float*)d_in[1];
  const float* feat   = (const float*)d_in[2];
  const float* Wt     = (const float*)d_in[3];
  const float* cbias  = (const float*)d_in[4];

  float* out = (float*)d_out;
  float* out_loss   = out;
  float* out_pobj   = out + 1;
  float* out_boxes  = out_pobj + NB*MVOX;
  float* out_scores = out_boxes + NB*KP*6;
  float* out_keep   = out_scores + NB*KP;
  float* out_ovr    = out_keep + NB*KP;

  float* pred     = (float*)d_ws;                 // NB*MVOX*7
  float* partials = pred + (size_t)NB*MVOX*7;     // 2*432*5
  float* tval     = partials + 2*BLK_PER_BATCH*5; // NB*KP
  int*   tidx     = (int*)(tval + NB*KP);         // NB*KP

  conv_kernel<<<dim3(6,6,12), dim3(8,8,8), 0, stream>>>(feat, Wt, cbias, pred);
  loss_kernel<<<dim3(2*BLK_PER_BATCH), dim3(256), 0, stream>>>(pred, lrt, scores, out_pobj, partials);
  finalize_kernel<<<dim3(1), dim3(64), 0, stream>>>(partials, out_loss);
  topk_kernel<<<dim3(NB), dim3(1024), 0, stream>>>(out_pobj, tval, tidx);
  nms_kernel<<<dim3(NB), dim3(128), 0, stream>>>(pred, tval, tidx, lrt, scores,
                                                 out_boxes, out_scores, out_keep, out_ovr);
}